// Round 5
// baseline (21446.759 us; speedup 1.0000x reference)
//
#include <hip/hip_runtime.h>
#include <math.h>

#define T_STEPS 512
#define BATCH   64
#define INDIM   512
#define MEMDIM  512
#define NWG     256

// WG wg owns memory dims {2wg, 2wg+1} -> 8 gate rows (i,o,u,f per m).
// Weights cached in LDS (padded rows -> conflict-free semi-broadcast reads).
// h/x read directly from global (L2) as float4, 8-distinct-line pattern.
// c state lives in LDS for the whole scan. Grid barrier: epoch counter in ws.

extern "C" __global__ void __launch_bounds__(256, 1)
lstm_scan(const float* __restrict__ inputs, const float* __restrict__ h0,
          const float* __restrict__ c0,
          const float* __restrict__ W_ioux, const float* __restrict__ b_ioux,
          const float* __restrict__ W_iouh, const float* __restrict__ b_iouh,
          const float* __restrict__ W_fx,   const float* __restrict__ b_fx,
          const float* __restrict__ W_fh,   const float* __restrict__ b_fh,
          float* __restrict__ out, int* __restrict__ bar)
{
    __shared__ float W_s[8][1028];     // 8 gate rows x K=1024 (x | h), pad->bank tile
    __shared__ float gates_s[8][65];
    __shared__ float c_s[2][64];
    __shared__ float bias_s[8];

    const int tid  = threadIdx.x;
    const int wg   = blockIdx.x;
    const int lane = tid & 63;
    const int wv   = tid >> 6;          // wave 0..3
    const int j8   = lane & 7;          // gate-row within WG
    const int bsub = lane >> 3;         // 0..7
    const int b0   = 16 * wv + bsub;    // batch rows handled by this thread
    const int b1   = b0 + 8;

    // ---- stage weights into LDS (once; reused 512 steps) ----
    for (int i = tid; i < 8 * 256; i += 256) {   // 256 float4 per row
        int row = i >> 8;
        int c4  = i & 255;
        int mloc = row >> 2, gate = row & 3;
        int mg = 2 * wg + mloc;
        const float* src;
        if (c4 < 128) {  // x-side weight
            const float* Wx = (gate < 3) ? (W_ioux + (size_t)(gate * 512 + mg) * INDIM)
                                         : (W_fx   + (size_t)mg * INDIM);
            src = Wx + c4 * 4;
        } else {         // h-side weight
            const float* Wh = (gate < 3) ? (W_iouh + (size_t)(gate * 512 + mg) * MEMDIM)
                                         : (W_fh   + (size_t)mg * MEMDIM);
            src = Wh + (c4 - 128) * 4;
        }
        float4 v = *(const float4*)src;
        *(float4*)&W_s[row][c4 * 4] = v;
    }
    if (tid < 8) {
        int mloc = tid >> 2, gate = tid & 3, mg = 2 * wg + mloc;
        bias_s[tid] = (gate < 3) ? (b_ioux[gate * 512 + mg] + b_iouh[gate * 512 + mg])
                                 : (b_fx[mg] + b_fh[mg]);
    }
    if (tid < 128) {
        int mloc = tid >> 6, b = tid & 63;
        c_s[mloc][b] = c0[b * MEMDIM + 2 * wg + mloc];
    }
    __syncthreads();

    const float4* wrow = (const float4*)&W_s[j8][0];   // 257 float4 (row padded)

    for (int t = 0; t < T_STEPS; ++t) {
        const float* hprev = (t == 0) ? h0 : (out + (size_t)(t - 1) * BATCH * MEMDIM);
        const float4* x0p = (const float4*)(inputs + ((size_t)t * BATCH + b0) * INDIM);
        const float4* x1p = (const float4*)(inputs + ((size_t)t * BATCH + b1) * INDIM);
        const float4* h0p = (const float4*)(hprev + (size_t)b0 * MEMDIM);
        const float4* h1p = (const float4*)(hprev + (size_t)b1 * MEMDIM);

        float4 a0 = make_float4(0.f, 0.f, 0.f, 0.f);
        float4 a1 = make_float4(0.f, 0.f, 0.f, 0.f);

#pragma unroll 4
        for (int k4 = 0; k4 < 128; ++k4) {        // x-side: K 0..511
            float4 w  = wrow[k4];
            float4 v0 = x0p[k4];
            float4 v1 = x1p[k4];
            a0.x += v0.x * w.x; a0.y += v0.y * w.y; a0.z += v0.z * w.z; a0.w += v0.w * w.w;
            a1.x += v1.x * w.x; a1.y += v1.y * w.y; a1.z += v1.z * w.z; a1.w += v1.w * w.w;
        }
#pragma unroll 4
        for (int k4 = 0; k4 < 128; ++k4) {        // h-side: K 512..1023
            float4 w  = wrow[128 + k4];
            float4 v0 = h0p[k4];
            float4 v1 = h1p[k4];
            a0.x += v0.x * w.x; a0.y += v0.y * w.y; a0.z += v0.z * w.z; a0.w += v0.w * w.w;
            a1.x += v1.x * w.x; a1.y += v1.y * w.y; a1.z += v1.z * w.z; a1.w += v1.w * w.w;
        }

        float bia = bias_s[j8];
        gates_s[j8][b0] = a0.x + a0.y + a0.z + a0.w + bia;
        gates_s[j8][b1] = a1.x + a1.y + a1.z + a1.w + bia;
        __syncthreads();

        if (tid < 128) {
            int mloc = tid >> 6, b = tid & 63;
            float iv = gates_s[mloc * 4 + 0][b];
            float ov = gates_s[mloc * 4 + 1][b];
            float uv = gates_s[mloc * 4 + 2][b];
            float fv = gates_s[mloc * 4 + 3][b];
            float ig = 1.f / (1.f + expf(-iv));
            float og = 1.f / (1.f + expf(-ov));
            float ug = tanhf(uv);
            float fg = 1.f / (1.f + expf(-fv));
            float cn = ig * ug + fg * c_s[mloc][b];
            c_s[mloc][b] = cn;
            float hn = og * tanhf(cn);
            int mg = 2 * wg + mloc;
            out[((size_t)t * BATCH + b) * MEMDIM + mg] = hn;
            if (t == T_STEPS - 1) {
                out[(size_t)T_STEPS * BATCH * MEMDIM + (size_t)b * MEMDIM + mg] = cn;  // c_final
                out[(size_t)T_STEPS * BATCH * MEMDIM + (size_t)BATCH * MEMDIM
                    + (size_t)b * MEMDIM + mg] = hn;                                   // h_final
            }
        }
        __syncthreads();

        // ---- device-wide epoch barrier (agent scope; XCD L2s not coherent) ----
        if (tid == 0) {
            int n = __hip_atomic_fetch_add(&bar[0], 1, __ATOMIC_ACQ_REL,
                                           __HIP_MEMORY_SCOPE_AGENT);
            if (n == NWG * (t + 1) - 1) {
                __hip_atomic_store(&bar[1], t + 1, __ATOMIC_RELEASE,
                                   __HIP_MEMORY_SCOPE_AGENT);
            } else {
                while (__hip_atomic_load(&bar[1], __ATOMIC_RELAXED,
                                         __HIP_MEMORY_SCOPE_AGENT) < t + 1) {
                    __builtin_amdgcn_s_sleep(1);
                }
                // acquire ordering on the synchronizing load
                (void)__hip_atomic_load(&bar[1], __ATOMIC_ACQUIRE,
                                        __HIP_MEMORY_SCOPE_AGENT);
            }
        }
        __syncthreads();
    }
}

extern "C" void kernel_launch(void* const* d_in, const int* in_sizes, int n_in,
                              void* d_out, int out_size, void* d_ws, size_t ws_size,
                              hipStream_t stream) {
    (void)in_sizes; (void)n_in; (void)out_size; (void)ws_size;
    const float* inputs = (const float*)d_in[0];
    const float* h0     = (const float*)d_in[1];
    const float* c0     = (const float*)d_in[2];
    const float* W_ioux = (const float*)d_in[3];
    const float* b_ioux = (const float*)d_in[4];
    const float* W_iouh = (const float*)d_in[5];
    const float* b_iouh = (const float*)d_in[6];
    const float* W_fx   = (const float*)d_in[7];
    const float* b_fx   = (const float*)d_in[8];
    const float* W_fh   = (const float*)d_in[9];
    const float* b_fh   = (const float*)d_in[10];
    float* out = (float*)d_out;
    int*   bar = (int*)d_ws;

    // zero the barrier state (ws is poisoned 0xAA before every launch)
    (void)hipMemsetAsync(d_ws, 0, 256, stream);

    void* args[] = { (void*)&inputs, (void*)&h0, (void*)&c0,
                     (void*)&W_ioux, (void*)&b_ioux, (void*)&W_iouh, (void*)&b_iouh,
                     (void*)&W_fx, (void*)&b_fx, (void*)&W_fh, (void*)&b_fh,
                     (void*)&out, (void*)&bar };

    hipError_t err = hipLaunchCooperativeKernel((const void*)lstm_scan,
                                                dim3(NWG), dim3(256),
                                                args, 0, stream);
    if (err != hipSuccess) {
        // fallback: plain launch (grid == CU count, 1 WG/CU -> co-resident)
        hipLaunchKernelGGL(lstm_scan, dim3(NWG), dim3(256), 0, stream,
                           inputs, h0, c0, W_ioux, b_ioux, W_iouh, b_iouh,
                           W_fx, b_fx, W_fh, b_fh, out, bar);
    }
}

// Round 6
// 12357.971 us; speedup vs baseline: 1.7355x; 1.7355x over previous
//
#include <hip/hip_runtime.h>
#include <math.h>

#define T_STEPS 512
#define BATCH   64
#define INDIM   512
#define MEMDIM  512
#define NWG     256
#define NT      1024

// WG wg owns memory dims {2wg, 2wg+1} -> 8 gate rows (i,o,u,f per m).
// 1024 threads: tid = q*256 + r; q = K-quarter (0..3), r gives (j8, bsub, wv)
// as before. Each thread dots 2 batch rows over a 128-dim K-quarter (x) and a
// 128-dim K-quarter (h); partials reduced through LDS. Weights stationary in
// LDS; c in LDS; h ping-pongs through `out` (L2/IF$). Per-step device barrier:
// two-level tree (16 leaves x 16 WGs) + epoch flag, acq/rel atomics.
// x-dot for step t is computed BEFORE waiting on epoch t (no serial dep).

extern "C" __global__ void __launch_bounds__(NT, 4)
lstm_scan(const float* __restrict__ inputs, const float* __restrict__ h0,
          const float* __restrict__ c0,
          const float* __restrict__ W_ioux, const float* __restrict__ b_ioux,
          const float* __restrict__ W_iouh, const float* __restrict__ b_iouh,
          const float* __restrict__ W_fx,   const float* __restrict__ b_fx,
          const float* __restrict__ W_fh,   const float* __restrict__ b_fh,
          float* __restrict__ out, int* __restrict__ bar)
{
    __shared__ __align__(16) float W_s[8][1028];  // 8 gate rows x 1024 (x|h), padded
    __shared__ float part_s[4][8][68];            // K-quarter partials (68: 2-way banks)
    __shared__ float c_s[2][64];
    __shared__ float bias_s[8];

    const int tid  = threadIdx.x;
    const int wg   = blockIdx.x;
    const int q    = tid >> 8;          // K-quarter 0..3
    const int r    = tid & 255;
    const int j8   = r & 7;             // gate row within WG
    const int bsub = (r >> 3) & 7;
    const int wv   = r >> 6;            // 0..3
    const int b0   = 16 * wv + bsub;
    const int b1   = b0 + 8;

    // ---- stage weights into LDS (once; reused 512 steps) ----
    for (int i = tid; i < 8 * 256; i += NT) {   // 256 float4 per row
        int row = i >> 8;
        int c4  = i & 255;
        int mloc = row >> 2, gate = row & 3;
        int mg = 2 * wg + mloc;
        const float* src;
        if (c4 < 128) {  // x-side weight
            const float* Wx = (gate < 3) ? (W_ioux + (size_t)(gate * 512 + mg) * INDIM)
                                         : (W_fx   + (size_t)mg * INDIM);
            src = Wx + c4 * 4;
        } else {         // h-side weight
            const float* Wh = (gate < 3) ? (W_iouh + (size_t)(gate * 512 + mg) * MEMDIM)
                                         : (W_fh   + (size_t)mg * MEMDIM);
            src = Wh + (c4 - 128) * 4;
        }
        float4 v = *(const float4*)src;
        *(float4*)&W_s[row][c4 * 4] = v;
    }
    if (tid < 8) {
        int mloc = tid >> 2, gate = tid & 3, mg = 2 * wg + mloc;
        bias_s[tid] = (gate < 3) ? (b_ioux[gate * 512 + mg] + b_iouh[gate * 512 + mg])
                                 : (b_fx[mg] + b_fh[mg]);
    }
    if (tid < 128) {
        int mloc = tid >> 6, b = tid & 63;
        c_s[mloc][b] = c0[b * MEMDIM + 2 * wg + mloc];
    }
    __syncthreads();

    const float4* wrowx = (const float4*)&W_s[j8][0] + q * 32;        // x quarter
    const float4* wrowh = (const float4*)&W_s[j8][0] + 128 + q * 32;  // h quarter

    for (int t = 0; t < T_STEPS; ++t) {
        // ---- x-side dot for step t (independent of h; overlaps barrier) ----
        const float4* x0p = (const float4*)(inputs + ((size_t)t * BATCH + b0) * INDIM) + q * 32;
        const float4* x1p = (const float4*)(inputs + ((size_t)t * BATCH + b1) * INDIM) + q * 32;
        float4 a0 = make_float4(0.f, 0.f, 0.f, 0.f);
        float4 a1 = make_float4(0.f, 0.f, 0.f, 0.f);
#pragma unroll 8
        for (int k = 0; k < 32; ++k) {
            float4 w  = wrowx[k];
            float4 v0 = x0p[k];
            float4 v1 = x1p[k];
            a0.x += v0.x * w.x; a0.y += v0.y * w.y; a0.z += v0.z * w.z; a0.w += v0.w * w.w;
            a1.x += v1.x * w.x; a1.y += v1.y * w.y; a1.z += v1.z * w.z; a1.w += v1.w * w.w;
        }

        // ---- wait for h_{t-1} (epoch t) ----
        if (t > 0) {
            if (tid == 0) {
                while (__hip_atomic_load(&bar[544], __ATOMIC_RELAXED,
                                         __HIP_MEMORY_SCOPE_AGENT) < t) {
                    __builtin_amdgcn_s_sleep(1);
                }
                (void)__hip_atomic_load(&bar[544], __ATOMIC_ACQUIRE,
                                        __HIP_MEMORY_SCOPE_AGENT);
            }
            __syncthreads();
        }

        // ---- h-side dot ----
        const float* hprev = (t == 0) ? h0 : (out + (size_t)(t - 1) * BATCH * MEMDIM);
        const float4* h0p = (const float4*)(hprev + (size_t)b0 * MEMDIM) + q * 32;
        const float4* h1p = (const float4*)(hprev + (size_t)b1 * MEMDIM) + q * 32;
#pragma unroll 8
        for (int k = 0; k < 32; ++k) {
            float4 w  = wrowh[k];
            float4 v0 = h0p[k];
            float4 v1 = h1p[k];
            a0.x += v0.x * w.x; a0.y += v0.y * w.y; a0.z += v0.z * w.z; a0.w += v0.w * w.w;
            a1.x += v1.x * w.x; a1.y += v1.y * w.y; a1.z += v1.z * w.z; a1.w += v1.w * w.w;
        }
        part_s[q][j8][b0] = a0.x + a0.y + a0.z + a0.w;
        part_s[q][j8][b1] = a1.x + a1.y + a1.z + a1.w;
        __syncthreads();

        // ---- epilogue: reduce quarters, activations, c/h update ----
        if (tid < 128) {
            int mloc = tid >> 6, b = tid & 63;
            int gr = mloc * 4;
            float iv = part_s[0][gr+0][b] + part_s[1][gr+0][b] + part_s[2][gr+0][b] + part_s[3][gr+0][b] + bias_s[gr+0];
            float ov = part_s[0][gr+1][b] + part_s[1][gr+1][b] + part_s[2][gr+1][b] + part_s[3][gr+1][b] + bias_s[gr+1];
            float uv = part_s[0][gr+2][b] + part_s[1][gr+2][b] + part_s[2][gr+2][b] + part_s[3][gr+2][b] + bias_s[gr+2];
            float fv = part_s[0][gr+3][b] + part_s[1][gr+3][b] + part_s[2][gr+3][b] + part_s[3][gr+3][b] + bias_s[gr+3];
            float ig = 1.f / (1.f + expf(-iv));
            float og = 1.f / (1.f + expf(-ov));
            float ug = tanhf(uv);
            float fg = 1.f / (1.f + expf(-fv));
            float cn = ig * ug + fg * c_s[mloc][b];
            c_s[mloc][b] = cn;
            float hn = og * tanhf(cn);
            int mg = 2 * wg + mloc;
            out[((size_t)t * BATCH + b) * MEMDIM + mg] = hn;
            if (t == T_STEPS - 1) {
                out[(size_t)T_STEPS * BATCH * MEMDIM + (size_t)b * MEMDIM + mg] = cn;  // c_final
                out[(size_t)T_STEPS * BATCH * MEMDIM + (size_t)BATCH * MEMDIM
                    + (size_t)b * MEMDIM + mg] = hn;                                   // h_final
            }
        }
        __syncthreads();   // h stores drained (vmcnt) before arrival

        // ---- arrive: two-level tree barrier (16 leaves x 16 WGs) ----
        // leaves at bar[g*32] (128B apart), root at bar[512], epoch flag bar[544]
        if (tid == 0) {
            int g = wg >> 4;
            int n = __hip_atomic_fetch_add(&bar[g * 32], 1, __ATOMIC_ACQ_REL,
                                           __HIP_MEMORY_SCOPE_AGENT);
            if (n == 16 * (t + 1) - 1) {            // last WG of this leaf
                int m = __hip_atomic_fetch_add(&bar[512], 1, __ATOMIC_ACQ_REL,
                                               __HIP_MEMORY_SCOPE_AGENT);
                if (m == 16 * (t + 1) - 1) {        // last leaf
                    __hip_atomic_store(&bar[544], t + 1, __ATOMIC_RELEASE,
                                       __HIP_MEMORY_SCOPE_AGENT);
                }
            }
        }
    }
}

extern "C" void kernel_launch(void* const* d_in, const int* in_sizes, int n_in,
                              void* d_out, int out_size, void* d_ws, size_t ws_size,
                              hipStream_t stream) {
    (void)in_sizes; (void)n_in; (void)out_size; (void)ws_size;
    const float* inputs = (const float*)d_in[0];
    const float* h0     = (const float*)d_in[1];
    const float* c0     = (const float*)d_in[2];
    const float* W_ioux = (const float*)d_in[3];
    const float* b_ioux = (const float*)d_in[4];
    const float* W_iouh = (const float*)d_in[5];
    const float* b_iouh = (const float*)d_in[6];
    const float* W_fx   = (const float*)d_in[7];
    const float* b_fx   = (const float*)d_in[8];
    const float* W_fh   = (const float*)d_in[9];
    const float* b_fh   = (const float*)d_in[10];
    float* out = (float*)d_out;
    int*   bar = (int*)d_ws;

    // zero barrier state (ws is poisoned 0xAA before every launch)
    (void)hipMemsetAsync(d_ws, 0, 4096, stream);

    void* args[] = { (void*)&inputs, (void*)&h0, (void*)&c0,
                     (void*)&W_ioux, (void*)&b_ioux, (void*)&W_iouh, (void*)&b_iouh,
                     (void*)&W_fx, (void*)&b_fx, (void*)&W_fh, (void*)&b_fh,
                     (void*)&out, (void*)&bar };

    hipError_t err = hipLaunchCooperativeKernel((const void*)lstm_scan,
                                                dim3(NWG), dim3(NT),
                                                args, 0, stream);
    if (err != hipSuccess) {
        // fallback: plain launch (grid == CU count, 1 WG/CU -> co-resident)
        hipLaunchKernelGGL(lstm_scan, dim3(NWG), dim3(NT), 0, stream,
                           inputs, h0, c0, W_ioux, b_ioux, W_iouh, b_iouh,
                           W_fx, b_fx, W_fh, b_fh, out, bar);
    }
}